// Round 1
// baseline (3277.385 us; speedup 1.0000x reference)
//
#include <hip/hip_runtime.h>

#define THREADS 256

// ---------------------------------------------------------------------------
// Detect whether the raw index array is int64 (high words all zero) or int32.
// Values are in [0, 50000) so for int64 every odd 32-bit word is 0.
// For int32 random data the odds of 2048 zeros is ~0.
// ---------------------------------------------------------------------------
__global__ void detect_i64(const unsigned* __restrict__ raw, int* __restrict__ flag) {
    __shared__ int nz;
    if (threadIdx.x == 0) nz = 0;
    __syncthreads();
    int found = 0;
    for (int i = threadIdx.x; i < 2048; i += blockDim.x) {
        if (raw[2 * i + 1] != 0u) found = 1;
    }
    if (found) atomicOr(&nz, 1);
    __syncthreads();
    if (threadIdx.x == 0) *flag = nz ? 0 : 1;  // 1 => int64
}

__global__ void convert_idx(const int* __restrict__ raw, int* __restrict__ out,
                            int n, const int* __restrict__ flag) {
    int i = blockIdx.x * blockDim.x + threadIdx.x;
    if (i < n) out[i] = (*flag) ? raw[2 * i] : raw[i];  // little-endian low word
}

// ---------------------------------------------------------------------------
// Degree count (incoming edges); self-loop added in compute_dis.
// ---------------------------------------------------------------------------
__global__ void count_deg(const int* __restrict__ dst, int E, int* __restrict__ deg) {
    int i = blockIdx.x * blockDim.x + threadIdx.x;
    if (i < E) atomicAdd(&deg[dst[i]], 1);
}

__global__ void compute_dis(const int* __restrict__ deg, float* __restrict__ dis, int n) {
    int i = blockIdx.x * blockDim.x + threadIdx.x;
    if (i < n) dis[i] = rsqrtf((float)(deg[i] + 1));  // +1 self-loop
}

// ---------------------------------------------------------------------------
// out[n][64] = in[n][64] @ W[64][64].  4 nodes per 256-thread block.
// ---------------------------------------------------------------------------
__global__ __launch_bounds__(256) void linear64(const float* __restrict__ in,
                                                const float* __restrict__ W,
                                                float* __restrict__ out, int n) {
    __shared__ float sW[64][64];
    __shared__ float sIn[4][64];
    int t = threadIdx.x;
    for (int i = t; i < 4096; i += 256) sW[i >> 6][i & 63] = W[i];
    int node0 = blockIdx.x * 4;
    {
        int nd = node0 + (t >> 6);
        sIn[t >> 6][t & 63] = (nd < n) ? in[nd * 64 + (t & 63)] : 0.f;
    }
    __syncthreads();
    int ln = t >> 6, od = t & 63;
    int node = node0 + ln;
    if (node < n) {
        float acc = 0.f;
#pragma unroll
        for (int k = 0; k < 64; k++) acc += sIn[ln][k] * sW[k][od];
        out[node * 64 + od] = acc;
    }
}

// ---------------------------------------------------------------------------
// agg[i][:] = h[i][:] * dis[i]^2   (self-loop message; full write, no memset)
// One thread per float4 (16 per node).
// ---------------------------------------------------------------------------
__global__ void self_init(const float* __restrict__ h, const float* __restrict__ dis,
                          float* __restrict__ agg, int n) {
    int i = blockIdx.x * blockDim.x + threadIdx.x;
    int tot = n * 16;
    if (i < tot) {
        int node = i >> 4;
        float w = dis[node];
        w *= w;
        float4 v = ((const float4*)h)[i];
        v.x *= w; v.y *= w; v.z *= w; v.w *= w;
        ((float4*)agg)[i] = v;
    }
}

// ---------------------------------------------------------------------------
// Edge scatter: agg[dst] += h[src] * dis[src]*dis[dst].  16 threads/edge,
// each thread handles one float4 slice (4 atomics).
// ---------------------------------------------------------------------------
__global__ __launch_bounds__(256) void edge_agg(const float* __restrict__ h,
                                                const int* __restrict__ src,
                                                const int* __restrict__ dst,
                                                const float* __restrict__ dis,
                                                float* __restrict__ agg, int E) {
    long long gid = (long long)blockIdx.x * blockDim.x + threadIdx.x;
    int e = (int)(gid >> 4);
    int sub = (int)(gid & 15);
    if (e < E) {
        int s = src[e], d = dst[e];
        float w = dis[s] * dis[d];
        float4 v = ((const float4*)(h + (long long)s * 64))[sub];
        float* p = agg + (long long)d * 64 + sub * 4;
        atomicAdd(p + 0, v.x * w);
        atomicAdd(p + 1, v.y * w);
        atomicAdd(p + 2, v.z * w);
        atomicAdd(p + 3, v.w * w);
    }
}

__global__ void bias_relu(float* __restrict__ a, const float* __restrict__ b, int n64) {
    int i = blockIdx.x * blockDim.x + threadIdx.x;
    if (i < n64) {
        float v = a[i] + b[i & 63];
        a[i] = v > 0.f ? v : 0.f;
    }
}

// ---------------------------------------------------------------------------
// Mean-pool (sum part): psum[batch[node]] += h[node], pcnt[g] += 1.
// ---------------------------------------------------------------------------
__global__ void pool_sum(const float* __restrict__ h, const int* __restrict__ batch,
                         float* __restrict__ psum, int* __restrict__ pcnt, int n) {
    int gid = blockIdx.x * blockDim.x + threadIdx.x;
    int node = gid >> 4, sub = gid & 15;
    if (node < n) {
        int g = batch[node];
        float4 v = ((const float4*)(h + (long long)node * 64))[sub];
        float* p = psum + g * 64 + sub * 4;
        atomicAdd(p + 0, v.x);
        atomicAdd(p + 1, v.y);
        atomicAdd(p + 2, v.z);
        atomicAdd(p + 3, v.w);
        if (sub == 0) atomicAdd(&pcnt[g], 1);
    }
}

// ---------------------------------------------------------------------------
// out[64][10] = (psum/cnt) @ Wfc + bfc.  One block of 640 threads.
// ---------------------------------------------------------------------------
__global__ __launch_bounds__(640) void final_fc(const float* __restrict__ psum,
                                                const int* __restrict__ pcnt,
                                                const float* __restrict__ Wfc,
                                                const float* __restrict__ bfc,
                                                float* __restrict__ out) {
    __shared__ float sP[64 * 64];
    __shared__ float sW[64 * 10];
    int t = threadIdx.x;
    for (int i = t; i < 4096; i += 640) sP[i] = psum[i];
    if (t < 640) sW[t] = Wfc[t];
    __syncthreads();
    int g = t / 10, c = t % 10;
    float acc = 0.f;
#pragma unroll
    for (int k = 0; k < 64; k++) acc += sP[g * 64 + k] * sW[k * 10 + c];
    float cnt = (float)pcnt[g];
    if (cnt < 1.f) cnt = 1.f;
    out[g * 10 + c] = acc / cnt + bfc[c];
}

static inline int cdiv(long long a, int b) { return (int)((a + b - 1) / b); }

extern "C" void kernel_launch(void* const* d_in, const int* in_sizes, int n_in,
                              void* d_out, int out_size, void* d_ws, size_t ws_size,
                              hipStream_t stream) {
    const float* x    = (const float*)d_in[0];
    const void*  eraw = d_in[1];
    const void*  braw = d_in[2];
    const float* W1   = (const float*)d_in[3];
    const float* b1   = (const float*)d_in[4];
    const float* W2   = (const float*)d_in[5];
    const float* b2   = (const float*)d_in[6];
    const float* Wfc  = (const float*)d_in[7];
    const float* bfc  = (const float*)d_in[8];
    float* out = (float*)d_out;

    const int N = in_sizes[0] / 64;   // 50000
    const int E = in_sizes[1] / 2;    // 1600000

    // ---- workspace carve (all offsets 256B-aligned) ----
    char* p = (char*)d_ws;
    int* flag = (int*)p;                    p += 256;
    int* idx  = (int*)p;                    p += (size_t)2 * E * sizeof(int);   // src=[0,E), dst=[E,2E)
    int* batchi = (int*)p;                  p += ((size_t)N * sizeof(int) + 255) / 256 * 256;
    int* deg  = (int*)p;                    p += ((size_t)N * sizeof(int) + 255) / 256 * 256;
    float* dis = (float*)p;                 p += ((size_t)N * sizeof(float) + 255) / 256 * 256;
    float* bufA = (float*)p;                p += (size_t)N * 64 * sizeof(float);
    float* bufB = (float*)p;                p += (size_t)N * 64 * sizeof(float);
    float* psum = (float*)p;                p += 64 * 64 * sizeof(float);
    int* pcnt = (int*)p;                    p += 256;

    // ---- zero the atomic accumulators ----
    hipMemsetAsync(deg, 0, (size_t)N * sizeof(int), stream);
    hipMemsetAsync(psum, 0, 64 * 64 * sizeof(float), stream);
    hipMemsetAsync(pcnt, 0, 64 * sizeof(int), stream);

    // ---- index dtype normalize ----
    detect_i64<<<1, THREADS, 0, stream>>>((const unsigned*)eraw, flag);
    convert_idx<<<cdiv(2LL * E, THREADS), THREADS, 0, stream>>>((const int*)eraw, idx, 2 * E, flag);
    convert_idx<<<cdiv(N, THREADS), THREADS, 0, stream>>>((const int*)braw, batchi, N, flag);
    int* srcI = idx;
    int* dstI = idx + E;

    // ---- degree / normalization ----
    count_deg<<<cdiv(E, THREADS), THREADS, 0, stream>>>(dstI, E, deg);
    compute_dis<<<cdiv(N, THREADS), THREADS, 0, stream>>>(deg, dis, N);

    // ---- layer 1 ----
    linear64<<<cdiv(N, 4), 256, 0, stream>>>(x, W1, bufA, N);
    self_init<<<cdiv((long long)N * 16, THREADS), THREADS, 0, stream>>>(bufA, dis, bufB, N);
    edge_agg<<<cdiv((long long)E * 16, THREADS), THREADS, 0, stream>>>(bufA, srcI, dstI, dis, bufB, E);
    bias_relu<<<cdiv((long long)N * 64, THREADS), THREADS, 0, stream>>>(bufB, b1, N * 64);

    // ---- layer 2 ----
    linear64<<<cdiv(N, 4), 256, 0, stream>>>(bufB, W2, bufA, N);
    self_init<<<cdiv((long long)N * 16, THREADS), THREADS, 0, stream>>>(bufA, dis, bufB, N);
    edge_agg<<<cdiv((long long)E * 16, THREADS), THREADS, 0, stream>>>(bufA, srcI, dstI, dis, bufB, E);
    bias_relu<<<cdiv((long long)N * 64, THREADS), THREADS, 0, stream>>>(bufB, b2, N * 64);

    // ---- pool + head ----
    pool_sum<<<cdiv((long long)N * 16, THREADS), THREADS, 0, stream>>>(bufB, batchi, psum, pcnt, N);
    final_fc<<<1, 640, 0, stream>>>(psum, pcnt, Wfc, bfc, out);
}

// Round 2
// 510.190 us; speedup vs baseline: 6.4238x; 6.4238x over previous
//
#include <hip/hip_runtime.h>

#define THREADS 256

// ---------------------------------------------------------------------------
// Detect whether the raw index array is int64 (high words all zero) or int32.
// ---------------------------------------------------------------------------
__global__ void detect_i64(const unsigned* __restrict__ raw, int* __restrict__ flag) {
    __shared__ int nz;
    if (threadIdx.x == 0) nz = 0;
    __syncthreads();
    int found = 0;
    for (int i = threadIdx.x; i < 2048; i += blockDim.x) {
        if (raw[2 * i + 1] != 0u) found = 1;
    }
    if (found) atomicOr(&nz, 1);
    __syncthreads();
    if (threadIdx.x == 0) *flag = nz ? 0 : 1;  // 1 => int64
}

// Convert edge indices (both halves) AND count in-degree for the dst half.
__global__ void convert_edges(const int* __restrict__ raw, int* __restrict__ out,
                              int E, int* __restrict__ deg, const int* __restrict__ flag) {
    int i = blockIdx.x * blockDim.x + threadIdx.x;
    int n2 = 2 * E;
    if (i < n2) {
        int v = (*flag) ? raw[2 * i] : raw[i];
        out[i] = v;
        if (i >= E) atomicAdd(&deg[v], 1);  // dst half
    }
}

__global__ void convert_idx(const int* __restrict__ raw, int* __restrict__ out,
                            int n, const int* __restrict__ flag) {
    int i = blockIdx.x * blockDim.x + threadIdx.x;
    if (i < n) out[i] = (*flag) ? raw[2 * i] : raw[i];
}

__global__ void compute_dis(const int* __restrict__ deg, float* __restrict__ dis, int n) {
    int i = blockIdx.x * blockDim.x + threadIdx.x;
    if (i < n) dis[i] = rsqrtf((float)(deg[i] + 1));  // +1 self-loop
}

// ---------------------------------------------------------------------------
// Exclusive scan of deg[0..n) -> off[0..n], three-phase.
// ---------------------------------------------------------------------------
__global__ __launch_bounds__(256) void scan_partial(const int* __restrict__ deg, int n,
                                                    int* __restrict__ partial) {
    __shared__ int s[256];
    int t = threadIdx.x;
    int i = blockIdx.x * 256 + t;
    s[t] = (i < n) ? deg[i] : 0;
    __syncthreads();
    for (int o = 128; o > 0; o >>= 1) {
        if (t < o) s[t] += s[t + o];
        __syncthreads();
    }
    if (t == 0) partial[blockIdx.x] = s[0];
}

__global__ __launch_bounds__(256) void scan_block(int* __restrict__ partial, int nb,
                                                  int* __restrict__ off, int n, int E) {
    __shared__ int s[256];
    int t = threadIdx.x;
    int v = (t < nb) ? partial[t] : 0;
    s[t] = v;
    __syncthreads();
    for (int o = 1; o < 256; o <<= 1) {
        int x = (t >= o) ? s[t - o] : 0;
        __syncthreads();
        s[t] += x;
        __syncthreads();
    }
    if (t < nb) partial[t] = s[t] - v;  // exclusive
    if (t == 0) off[n] = E;
}

__global__ __launch_bounds__(256) void scan_final(const int* __restrict__ deg, int n,
                                                  const int* __restrict__ partial,
                                                  int* __restrict__ off, int* __restrict__ cur) {
    __shared__ int s[256];
    int t = threadIdx.x;
    int i = blockIdx.x * 256 + t;
    int v = (i < n) ? deg[i] : 0;
    s[t] = v;
    __syncthreads();
    for (int o = 1; o < 256; o <<= 1) {
        int x = (t >= o) ? s[t - o] : 0;
        __syncthreads();
        s[t] += x;
        __syncthreads();
    }
    if (i < n) {
        int e = partial[blockIdx.x] + s[t] - v;  // exclusive
        off[i] = e;
        cur[i] = e;
    }
}

// Ticket scatter: sorted-by-dst src list.
__global__ void scatter_edges(const int* __restrict__ src, const int* __restrict__ dst,
                              int E, int* __restrict__ cur, int* __restrict__ ssrc) {
    int i = blockIdx.x * blockDim.x + threadIdx.x;
    if (i < E) {
        int d = dst[i];
        int pos = atomicAdd(&cur[d], 1);
        ssrc[pos] = src[i];
    }
}

// ---------------------------------------------------------------------------
// out[n][64] = dis[n] * (in[n][64] @ W[64][64]).  4 nodes / 256-thread block,
// 16 node-passes per block (W loaded to LDS once per block).
// ---------------------------------------------------------------------------
__global__ __launch_bounds__(256) void linear64(const float* __restrict__ in,
                                                const float* __restrict__ W,
                                                const float* __restrict__ dis,
                                                float* __restrict__ out, int n) {
    __shared__ float sW[64][64];
    __shared__ float sIn[4][64];
    int t = threadIdx.x;
    for (int i = t; i < 4096; i += 256) sW[i >> 6][i & 63] = W[i];
    int ln = t >> 6, od = t & 63;
    int base = blockIdx.x * 64;  // 16 passes x 4 nodes
    for (int pass = 0; pass < 16; pass++) {
        int node0 = base + pass * 4;
        __syncthreads();
        {
            int nd = node0 + ln;
            sIn[ln][od] = (nd < n) ? in[(long long)nd * 64 + od] : 0.f;
        }
        __syncthreads();
        int node = node0 + ln;
        if (node < n) {
            float acc = 0.f;
#pragma unroll
            for (int k = 0; k < 64; k++) acc += sIn[ln][k] * sW[k][od];
            out[(long long)node * 64 + od] = acc * dis[node];
        }
    }
}

// ---------------------------------------------------------------------------
// Pull-style aggregation. hs = dis .* (h @ W) already prescaled.
// out[d][lane] = relu( dis[d] * ( sum_{s in N(d)} hs[s][lane] + hs[d][lane] ) + b[lane] )
// One wave (64 lanes) per dst node, lane = feature dim.
// ---------------------------------------------------------------------------
__global__ __launch_bounds__(256) void gather_agg(const float* __restrict__ hs,
                                                  const int* __restrict__ off,
                                                  const int* __restrict__ ssrc,
                                                  const float* __restrict__ dis,
                                                  const float* __restrict__ bias,
                                                  float* __restrict__ out, int n) {
    int t = threadIdx.x;
    int lane = t & 63;
    int node = blockIdx.x * 4 + (t >> 6);
    if (node >= n) return;
    int beg = off[node], end = off[node + 1];
    float acc = 0.f;
    int e = beg;
    for (; e + 4 <= end; e += 4) {
        int s0 = ssrc[e], s1 = ssrc[e + 1], s2 = ssrc[e + 2], s3 = ssrc[e + 3];
        float v0 = hs[(long long)s0 * 64 + lane];
        float v1 = hs[(long long)s1 * 64 + lane];
        float v2 = hs[(long long)s2 * 64 + lane];
        float v3 = hs[(long long)s3 * 64 + lane];
        acc += v0 + v1 + v2 + v3;
    }
    for (; e < end; e++) {
        acc += hs[(long long)ssrc[e] * 64 + lane];
    }
    acc += hs[(long long)node * 64 + lane];  // self-loop (weight dis[d]^2 = dis[d]*hs-scale)
    float v = dis[node] * acc + bias[lane];
    out[(long long)node * 64 + lane] = v > 0.f ? v : 0.f;
}

// ---------------------------------------------------------------------------
// Mean-pool sum: batch is sorted, so per-wave register accumulation with
// flush-on-graph-change. 32 nodes per wave, lane = dim.
// ---------------------------------------------------------------------------
__global__ __launch_bounds__(256) void pool_sum(const float* __restrict__ h,
                                                const int* __restrict__ batch,
                                                float* __restrict__ psum,
                                                int* __restrict__ pcnt, int n) {
    int t = threadIdx.x;
    int lane = t & 63;
    int base = (blockIdx.x * 4 + (t >> 6)) * 32;
    float acc = 0.f;
    int g = -1, cnt = 0;
    for (int i = 0; i < 32; i++) {
        int node = base + i;
        if (node >= n) break;
        int bg = batch[node];
        if (bg != g) {
            if (g >= 0) {
                atomicAdd(&psum[g * 64 + lane], acc);
                if (lane == 0) atomicAdd(&pcnt[g], cnt);
            }
            g = bg; acc = 0.f; cnt = 0;
        }
        acc += h[(long long)node * 64 + lane];
        cnt++;
    }
    if (g >= 0) {
        atomicAdd(&psum[g * 64 + lane], acc);
        if (lane == 0) atomicAdd(&pcnt[g], cnt);
    }
}

// ---------------------------------------------------------------------------
// out[64][10] = (psum/cnt) @ Wfc + bfc.  One block of 640 threads.
// ---------------------------------------------------------------------------
__global__ __launch_bounds__(640) void final_fc(const float* __restrict__ psum,
                                                const int* __restrict__ pcnt,
                                                const float* __restrict__ Wfc,
                                                const float* __restrict__ bfc,
                                                float* __restrict__ out) {
    __shared__ float sP[64 * 64];
    __shared__ float sW[64 * 10];
    int t = threadIdx.x;
    for (int i = t; i < 4096; i += 640) sP[i] = psum[i];
    if (t < 640) sW[t] = Wfc[t];
    __syncthreads();
    int g = t / 10, c = t % 10;
    float acc = 0.f;
#pragma unroll
    for (int k = 0; k < 64; k++) acc += sP[g * 64 + k] * sW[k * 10 + c];
    float cnt = (float)pcnt[g];
    if (cnt < 1.f) cnt = 1.f;
    out[g * 10 + c] = acc / cnt + bfc[c];
}

static inline int cdiv(long long a, int b) { return (int)((a + b - 1) / b); }

extern "C" void kernel_launch(void* const* d_in, const int* in_sizes, int n_in,
                              void* d_out, int out_size, void* d_ws, size_t ws_size,
                              hipStream_t stream) {
    const float* x    = (const float*)d_in[0];
    const void*  eraw = d_in[1];
    const void*  braw = d_in[2];
    const float* W1   = (const float*)d_in[3];
    const float* b1   = (const float*)d_in[4];
    const float* W2   = (const float*)d_in[5];
    const float* b2   = (const float*)d_in[6];
    const float* Wfc  = (const float*)d_in[7];
    const float* bfc  = (const float*)d_in[8];
    float* out = (float*)d_out;

    const int N = in_sizes[0] / 64;   // 50000
    const int E = in_sizes[1] / 2;    // 1600000
    const int NB = cdiv(N, 256);      // scan blocks (196)

    // ---- workspace carve (256B-aligned chunks) ----
    char* p = (char*)d_ws;
    auto carve = [&](size_t bytes) { char* q = p; p += (bytes + 255) / 256 * 256; return q; };
    int*   flag    = (int*)carve(4);
    int*   idx     = (int*)carve((size_t)2 * E * sizeof(int));   // src=[0,E), dst=[E,2E)
    int*   ssrc    = (int*)carve((size_t)E * sizeof(int));       // dst-sorted src list
    int*   batchi  = (int*)carve((size_t)N * sizeof(int));
    int*   deg     = (int*)carve((size_t)N * sizeof(int));
    int*   off     = (int*)carve((size_t)(N + 1) * sizeof(int));
    int*   cur     = (int*)carve((size_t)N * sizeof(int));
    int*   partial = (int*)carve((size_t)NB * sizeof(int));
    float* dis     = (float*)carve((size_t)N * sizeof(float));
    float* bufA    = (float*)carve((size_t)N * 64 * sizeof(float));
    float* bufB    = (float*)carve((size_t)N * 64 * sizeof(float));
    float* psum    = (float*)carve(64 * 64 * sizeof(float));
    int*   pcnt    = (int*)carve(64 * sizeof(int));

    // ---- zero atomic accumulators ----
    hipMemsetAsync(deg, 0, (size_t)N * sizeof(int), stream);
    hipMemsetAsync(psum, 0, 64 * 64 * sizeof(float), stream);
    hipMemsetAsync(pcnt, 0, 64 * sizeof(int), stream);

    // ---- index dtype normalize + degree count ----
    detect_i64<<<1, THREADS, 0, stream>>>((const unsigned*)eraw, flag);
    convert_edges<<<cdiv(2LL * E, THREADS), THREADS, 0, stream>>>((const int*)eraw, idx, E, deg, flag);
    convert_idx<<<cdiv(N, THREADS), THREADS, 0, stream>>>((const int*)braw, batchi, N, flag);
    int* srcI = idx;
    int* dstI = idx + E;

    compute_dis<<<cdiv(N, THREADS), THREADS, 0, stream>>>(deg, dis, N);

    // ---- CSR build: scan + ticket scatter ----
    scan_partial<<<NB, 256, 0, stream>>>(deg, N, partial);
    scan_block<<<1, 256, 0, stream>>>(partial, NB, off, N, E);
    scan_final<<<NB, 256, 0, stream>>>(deg, N, partial, off, cur);
    scatter_edges<<<cdiv(E, THREADS), THREADS, 0, stream>>>(srcI, dstI, E, cur, ssrc);

    // ---- layer 1: hs1 = dis .* (x @ W1); agg -> relu -> bufB ----
    linear64<<<cdiv(N, 64), 256, 0, stream>>>(x, W1, dis, bufA, N);
    gather_agg<<<cdiv(N, 4), 256, 0, stream>>>(bufA, off, ssrc, dis, b1, bufB, N);

    // ---- layer 2: hs2 = dis .* (bufB @ W2); agg -> relu -> bufA ----
    linear64<<<cdiv(N, 64), 256, 0, stream>>>(bufB, W2, dis, bufA, N);
    gather_agg<<<cdiv(N, 4), 256, 0, stream>>>(bufA, off, ssrc, dis, b2, bufB, N);

    // ---- pool + head ----
    pool_sum<<<cdiv(N, 128), 256, 0, stream>>>(bufB, batchi, psum, pcnt, N);
    final_fc<<<1, 640, 0, stream>>>(psum, pcnt, Wfc, bfc, out);
}